// Round 3
// baseline (3555.331 us; speedup 1.0000x reference)
//
#include <hip/hip_runtime.h>
#include <cmath>

// Problem constants (from reference setup_inputs)
#define HSZ   1024   // H == E == A == 1024
#define SSZ   2048   // encoder length S
#define VSZ   50257  // vocab
#define BOUND 25
#define SOS   1
#define NPART 1024   // logit argmax partials (= logit grid size)

// ---------------------------------------------------------------------------
// init: h0 = hidden[0]
// ---------------------------------------------------------------------------
__global__ __launch_bounds__(256) void init_kernel(const float* __restrict__ hidden,
                                                   float* __restrict__ h0) {
    int i = blockIdx.x * 256 + threadIdx.x;
    if (i < HSZ) h0[i] = hidden[i];
}

// ---------------------------------------------------------------------------
// eproj[s][a] = sum_k e[s][k] * W_e[a][k] + b_a[a]   (2048x1024x1024 fp32 GEMM)
// Retiled: BM=128 (s), BN=64 (a), BK=16; 256 threads; 8x4 micro-tile.
// Grid 16x16 = 256 blocks (1/CU). LDS 12 KB.
// ---------------------------------------------------------------------------
#define BM 128
#define BN 64
#define BK 16
__global__ __launch_bounds__(256) void eproj_kernel(const float* __restrict__ e,
                                                    const float* __restrict__ We,
                                                    const float* __restrict__ b_a,
                                                    float* __restrict__ eproj) {
    __shared__ __align__(16) float As[BK][BM];
    __shared__ __align__(16) float Bs[BK][BN];
    const int tid = threadIdx.x;
    const int tx = tid & 15;            // a-dir: 16 threads x 4 cols
    const int ty = tid >> 4;            // s-dir: 16 threads x 8 rows
    const int arow0 = blockIdx.x * BM;  // s-tile
    const int brow0 = blockIdx.y * BN;  // a-tile
    const int lr = tid >> 2;            // 0..63
    const int lc = (tid & 3) * 4;       // 0,4,8,12

    float acc[8][4] = {};
    for (int k0 = 0; k0 < HSZ; k0 += BK) {
        // stage A: 128 rows x 16 k  (two float4 per thread)
        float4 a0 = *(const float4*)&e[(size_t)(arow0 + lr) * HSZ + k0 + lc];
        float4 a1 = *(const float4*)&e[(size_t)(arow0 + lr + 64) * HSZ + k0 + lc];
        // stage B: 64 rows x 16 k   (one float4 per thread)
        float4 bv = *(const float4*)&We[(size_t)(brow0 + lr) * HSZ + k0 + lc];
        As[lc + 0][lr] = a0.x; As[lc + 1][lr] = a0.y;
        As[lc + 2][lr] = a0.z; As[lc + 3][lr] = a0.w;
        As[lc + 0][lr + 64] = a1.x; As[lc + 1][lr + 64] = a1.y;
        As[lc + 2][lr + 64] = a1.z; As[lc + 3][lr + 64] = a1.w;
        Bs[lc + 0][lr] = bv.x; Bs[lc + 1][lr] = bv.y;
        Bs[lc + 2][lr] = bv.z; Bs[lc + 3][lr] = bv.w;
        __syncthreads();
#pragma unroll
        for (int kk = 0; kk < BK; kk++) {
            float4 x0 = *(const float4*)&As[kk][ty * 8];
            float4 x1 = *(const float4*)&As[kk][ty * 8 + 4];
            float4 b4 = *(const float4*)&Bs[kk][tx * 4];
            float a[8] = {x0.x, x0.y, x0.z, x0.w, x1.x, x1.y, x1.z, x1.w};
            float b[4] = {b4.x, b4.y, b4.z, b4.w};
#pragma unroll
            for (int i = 0; i < 8; i++)
#pragma unroll
                for (int j = 0; j < 4; j++) acc[i][j] += a[i] * b[j];
        }
        __syncthreads();
    }
#pragma unroll
    for (int i = 0; i < 8; i++) {
        int s = arow0 + ty * 8 + i;
#pragma unroll
        for (int j = 0; j < 4; j++) {
            int a = brow0 + tx * 4 + j;
            eproj[(size_t)s * HSZ + a] = acc[i][j] + b_a[a];
        }
    }
}

// ---------------------------------------------------------------------------
// GRU cell, one block per hidden unit j. Folds the final argmax over the
// NPART logit partials at the head (all blocks redundantly; 8 KB L2-hot).
// float4 loads: thread t covers c = 4t..4t+3.   (Round-1-validated)
// ---------------------------------------------------------------------------
__global__ __launch_bounds__(256) void gru_kernel(const float* __restrict__ emb_table,
                                                  const float* __restrict__ W_ih,
                                                  const float* __restrict__ W_hh,
                                                  const float* __restrict__ b_ih,
                                                  const float* __restrict__ b_hh,
                                                  const float* __restrict__ h_old,
                                                  const float* __restrict__ pval,
                                                  const int* __restrict__ pidx,
                                                  int first,
                                                  float* __restrict__ h_new,
                                                  float* __restrict__ out_prev) {
    const int t = threadIdx.x;
    const int j = blockIdx.x;
    __shared__ float rv[256];
    __shared__ int ri[256];

    int word;
    if (!first) {
        float bv = -INFINITY; int bi = 0x7fffffff;
        for (int i = t; i < NPART; i += 256) {
            float v = pval[i]; int id = pidx[i];
            if (v > bv || (v == bv && id < bi)) { bv = v; bi = id; }
        }
        rv[t] = bv; ri[t] = bi;
        __syncthreads();
        for (int s2 = 128; s2 > 0; s2 >>= 1) {
            if (t < s2) {
                if (rv[t + s2] > rv[t] || (rv[t + s2] == rv[t] && ri[t + s2] < ri[t])) {
                    rv[t] = rv[t + s2]; ri[t] = ri[t + s2];
                }
            }
            __syncthreads();
        }
        word = ri[0];
        if (j == 0 && t == 0 && out_prev) *out_prev = (float)word;
    } else {
        word = SOS;
    }

    const float* __restrict__ x = emb_table + (size_t)word * HSZ;
    const int c = t * 4;
    float4 x4 = *(const float4*)&x[c];
    float4 h4 = *(const float4*)&h_old[c];
    float acc[6];
#pragma unroll
    for (int g = 0; g < 3; g++) {
        float4 wi = *(const float4*)&W_ih[(size_t)(g * HSZ + j) * HSZ + c];
        float4 wh = *(const float4*)&W_hh[(size_t)(g * HSZ + j) * HSZ + c];
        acc[g]     = wi.x * x4.x + wi.y * x4.y + wi.z * x4.z + wi.w * x4.w;
        acc[3 + g] = wh.x * h4.x + wh.y * h4.y + wh.z * h4.z + wh.w * h4.w;
    }
#pragma unroll
    for (int g = 0; g < 6; g++)
#pragma unroll
        for (int off = 32; off > 0; off >>= 1) acc[g] += __shfl_down(acc[g], off, 64);

    const int wave = t >> 6, lane = t & 63;
    __shared__ float wred[4][6];
    if (lane == 0) {
#pragma unroll
        for (int g = 0; g < 6; g++) wred[wave][g] = acc[g];
    }
    __syncthreads();
    if (t == 0) {
        float res[6];
#pragma unroll
        for (int g = 0; g < 6; g++)
            res[g] = wred[0][g] + wred[1][g] + wred[2][g] + wred[3][g];
        float ir = res[0] + b_ih[j];
        float iz = res[1] + b_ih[HSZ + j];
        float in_ = res[2] + b_ih[2 * HSZ + j];
        float hr = res[3] + b_hh[j];
        float hz = res[4] + b_hh[HSZ + j];
        float hn = res[5] + b_hh[2 * HSZ + j];
        float r = 1.f / (1.f + expf(-(ir + hr)));
        float z = 1.f / (1.f + expf(-(iz + hz)));
        float n = tanhf(in_ + r * hn);
        h_new[j] = (1.f - z) * n + z * h_old[j];
    }
}

// ---------------------------------------------------------------------------
// q[a] = sum_c W_q[a][c] * h[c]   (float4 + shfl; Round-1-validated)
// ---------------------------------------------------------------------------
__global__ __launch_bounds__(256) void q_kernel(const float* __restrict__ W_q,
                                                const float* __restrict__ h,
                                                float* __restrict__ q) {
    const int a = blockIdx.x, t = threadIdx.x;
    const int c = t * 4;
    float4 wq = *(const float4*)&W_q[(size_t)a * HSZ + c];
    float4 h4 = *(const float4*)&h[c];
    float acc = wq.x * h4.x + wq.y * h4.y + wq.z * h4.z + wq.w * h4.w;
#pragma unroll
    for (int off = 32; off > 0; off >>= 1) acc += __shfl_down(acc, off, 64);
    const int wave = t >> 6, lane = t & 63;
    __shared__ float wred[4];
    if (lane == 0) wred[wave] = acc;
    __syncthreads();
    if (t == 0) q[a] = wred[0] + wred[1] + wred[2] + wred[3];
}

// ---------------------------------------------------------------------------
// s[k] = sum_a tanh(eproj[k][a] + q[a]) * v_a[a]; blocks 0..3 zero ctx
// (consumed by attn_kernel atomics next launch).   (Round-1-validated)
// ---------------------------------------------------------------------------
__global__ __launch_bounds__(256) void score_kernel(const float* __restrict__ eproj,
                                                    const float* __restrict__ q,
                                                    const float* __restrict__ v_a,
                                                    float* __restrict__ s,
                                                    float* __restrict__ ctx) {
    const int k = blockIdx.x, t = threadIdx.x;
    if (k < 4) ctx[k * 256 + t] = 0.f;
    const int c = t * 4;
    float4 ev = *(const float4*)&eproj[(size_t)k * HSZ + c];
    float4 q4 = *(const float4*)&q[c];
    float4 v4 = *(const float4*)&v_a[c];
    float acc = tanhf(ev.x + q4.x) * v4.x + tanhf(ev.y + q4.y) * v4.y +
                tanhf(ev.z + q4.z) * v4.z + tanhf(ev.w + q4.w) * v4.w;
#pragma unroll
    for (int off = 32; off > 0; off >>= 1) acc += __shfl_down(acc, off, 64);
    const int wave = t >> 6, lane = t & 63;
    __shared__ float wred[4];
    if (lane == 0) wred[wave] = acc;
    __syncthreads();
    if (t == 0) s[k] = wred[0] + wred[1] + wred[2] + wred[3];
}

// ---------------------------------------------------------------------------
// attn: fused softmax + ctx. grid (32 k-chunks of 64, 4 col-chunks of 256).
// Every block redundantly computes softmax stats over all 2048 scores
// (8 KB read, L2-hot); y==0 blocks write out_w.   (Round-1-validated)
// ---------------------------------------------------------------------------
__global__ __launch_bounds__(256) void attn_kernel(const float* __restrict__ s,
                                                   const float* __restrict__ e,
                                                   float* __restrict__ ctx,
                                                   float* __restrict__ out_w) {
    const int t = threadIdx.x;
    const int kc = blockIdx.x;   // 0..31
    const int ac = blockIdx.y;   // 0..3
    __shared__ float red[256];

    float m = -INFINITY;
    for (int k = t; k < SSZ; k += 256) m = fmaxf(m, s[k]);
    red[t] = m;
    __syncthreads();
    for (int s2 = 128; s2 > 0; s2 >>= 1) {
        if (t < s2) red[t] = fmaxf(red[t], red[t + s2]);
        __syncthreads();
    }
    m = red[0];
    __syncthreads();

    float sum = 0.f;
    for (int k = t; k < SSZ; k += 256) sum += expf(s[k] - m);
    red[t] = sum;
    __syncthreads();
    for (int s2 = 128; s2 > 0; s2 >>= 1) {
        if (t < s2) red[t] += red[t + s2];
        __syncthreads();
    }
    float inv = 1.f / red[0];

    __shared__ float wch[64];
    if (t < 64) {
        float wv = expf(s[kc * 64 + t] - m) * inv;
        wch[t] = wv;
        if (ac == 0) out_w[kc * 64 + t] = wv;
    }
    __syncthreads();

    const int a = ac * 256 + t;
    float acc = 0.f;
#pragma unroll
    for (int k = 0; k < 64; k++)
        acc += wch[k] * e[(size_t)(kc * 64 + k) * HSZ + a];
    atomicAdd(&ctx[a], acc);
}

// ---------------------------------------------------------------------------
// logit partial argmax (Round-2 verbatim — proven at BW):
// merge in 32 VGPRs/lane; pure float4 row loads; 1024 blocks x 4 waves.
// ---------------------------------------------------------------------------
__global__ __launch_bounds__(256) void logit_kernel(const float* __restrict__ W_out,
                                                    const float* __restrict__ b_out,
                                                    const float* __restrict__ h,
                                                    const float* __restrict__ ctx,
                                                    float* __restrict__ pval,
                                                    int* __restrict__ pidx) {
    __shared__ float4 mrg[512];   // merge = [h, ctx], 2048 floats
    const int t = threadIdx.x;
    mrg[t]       = ((const float4*)h)[t];
    mrg[256 + t] = ((const float4*)ctx)[t];
    __syncthreads();

    const int wave = t >> 6, lane = t & 63;
    float4 m[8];
#pragma unroll
    for (int i = 0; i < 8; i++) m[i] = mrg[lane + 64 * i];

    const int gw = blockIdx.x * 4 + wave;    // 0..4095
    float best = -INFINITY;
    int bidx = 0x7fffffff;
    for (int v = gw; v < VSZ; v += 4096) {
        const float4* __restrict__ row = (const float4*)(W_out + (size_t)v * (2 * HSZ));
        float acc = 0.f;
#pragma unroll
        for (int i = 0; i < 8; i++) {
            float4 r = row[lane + 64 * i];
            acc += r.x * m[i].x + r.y * m[i].y + r.z * m[i].z + r.w * m[i].w;
        }
#pragma unroll
        for (int off = 32; off > 0; off >>= 1) acc += __shfl_down(acc, off, 64);
        if (lane == 0) {
            float logit = acc + b_out[v];
            if (logit > best) { best = logit; bidx = v; }   // v ascending → first-max kept
        }
    }
    __shared__ float bv[4];
    __shared__ int bi[4];
    if (lane == 0) { bv[wave] = best; bi[wave] = bidx; }
    __syncthreads();
    if (t == 0) {
        float B = bv[0]; int I = bi[0];
        for (int i = 1; i < 4; i++)
            if (bv[i] > B || (bv[i] == B && bi[i] < I)) { B = bv[i]; I = bi[i]; }
        pval[blockIdx.x] = B;
        pidx[blockIdx.x] = I;
    }
}

// ---------------------------------------------------------------------------
// epilogue: reduce last step's partials, write out[BOUND-1]
// ---------------------------------------------------------------------------
__global__ __launch_bounds__(256) void final_kernel(const float* __restrict__ pval,
                                                    const int* __restrict__ pidx,
                                                    float* __restrict__ out_word) {
    const int t = threadIdx.x;
    float bv = -INFINITY; int bi = 0x7fffffff;
    for (int i = t; i < NPART; i += 256) {
        float v = pval[i]; int id = pidx[i];
        if (v > bv || (v == bv && id < bi)) { bv = v; bi = id; }
    }
    __shared__ float rv[256];
    __shared__ int ri[256];
    rv[t] = bv; ri[t] = bi;
    __syncthreads();
    for (int s2 = 128; s2 > 0; s2 >>= 1) {
        if (t < s2) {
            if (rv[t + s2] > rv[t] || (rv[t + s2] == rv[t] && ri[t + s2] < ri[t])) {
                rv[t] = rv[t + s2]; ri[t] = ri[t + s2];
            }
        }
        __syncthreads();
    }
    if (t == 0) *out_word = (float)ri[0];
}

// ---------------------------------------------------------------------------
extern "C" void kernel_launch(void* const* d_in, const int* in_sizes, int n_in,
                              void* d_out, int out_size, void* d_ws, size_t ws_size,
                              hipStream_t stream) {
    const float* hidden     = (const float*)d_in[0];   // (1,1,1024)
    const float* embeddings = (const float*)d_in[1];   // (1,2048,1024)
    const float* emb_table  = (const float*)d_in[2];   // (50257,1024)
    const float* W_ih       = (const float*)d_in[3];   // (3072,1024)
    const float* W_hh       = (const float*)d_in[4];   // (3072,1024)
    const float* b_ih       = (const float*)d_in[5];   // (3072)
    const float* b_hh       = (const float*)d_in[6];   // (3072)
    const float* W_e        = (const float*)d_in[7];   // (1024,1024)
    const float* W_q        = (const float*)d_in[8];   // (1024,1024)
    const float* b_a        = (const float*)d_in[9];   // (1024)
    const float* v_a        = (const float*)d_in[10];  // (1024)
    const float* W_out      = (const float*)d_in[11];  // (50257,2048)
    const float* b_out      = (const float*)d_in[12];  // (50257)

    float* out = (float*)d_out;        // [0:25] words (as float), [25:] weights
    float* ws  = (float*)d_ws;

    // workspace layout (floats)
    float* eproj = ws;                          // 2048*1024
    float* h0    = ws + (size_t)SSZ * HSZ;      // 1024
    float* h1    = h0 + HSZ;                    // 1024
    float* qv    = h1 + HSZ;                    // 1024
    float* sc    = qv + HSZ;                    // 2048
    float* ctx   = sc + SSZ;                    // 1024
    float* pval  = ctx + HSZ;                   // NPART
    int*   pidx  = (int*)(pval + NPART);        // NPART

    init_kernel<<<4, 256, 0, stream>>>(hidden, h0);
    dim3 egrid(SSZ / BM, HSZ / BN);
    eproj_kernel<<<egrid, 256, 0, stream>>>(embeddings, W_e, b_a, eproj);

    for (int t = 0; t < BOUND; t++) {
        float* hold = (t & 1) ? h1 : h0;
        float* hnew = (t & 1) ? h0 : h1;
        gru_kernel<<<HSZ, 256, 0, stream>>>(emb_table, W_ih, W_hh, b_ih, b_hh,
                                            hold, pval, pidx, (t == 0) ? 1 : 0,
                                            hnew, (t > 0) ? out + (t - 1) : nullptr);
        q_kernel<<<HSZ, 256, 0, stream>>>(W_q, hnew, qv);
        score_kernel<<<SSZ, 256, 0, stream>>>(eproj, qv, v_a, sc, ctx);
        attn_kernel<<<dim3(32, 4), 256, 0, stream>>>(sc, embeddings, ctx,
                                                     out + BOUND + (size_t)t * SSZ);
        logit_kernel<<<1024, 256, 0, stream>>>(W_out, b_out, hnew, ctx, pval, pidx);
    }
    final_kernel<<<1, 256, 0, stream>>>(pval, pidx, out + (BOUND - 1));
}